// Round 8
// baseline (101.743 us; speedup 1.0000x reference)
//
#include <hip/hip_runtime.h>

// Chamfer, B=4, N=M=8192 fp32 -> scalar. Round 11: 32x32x16 chained-K MFMA.
// r8/r9/r10 post-mortem: density x2, occupancy x2, counted-vmcnt ring, setprio ALL
// neutral at ~36 us = ~10.5 cyc/CU per MFMA instr vs 4.6-cyc pipe cost. Theory: ~6 cyc
// per-INSTRUCTION overhead (issue + MFMA->min3 latency exposure) that schedule levers
// can't hide. Test: halve the instruction count -- one 32x32 tile = 2 chained
// v_mfma_f32_32x32x16_bf16 (K=16+16 covers the 30 slots; C-chain stays in matrix pipe):
// 1.049M instrs (was 2.097M) at 8.07 cyc -> floor 13.8 us. Same VALU-min, same DS count.
// Fragment maps (32-wide): A/B row|col = lane&31, k-half = lane>>5;
// C/D col = lane&31, row = (reg&3)+8*(reg>>2)+4*(lane>>5) [m74/m101].
// Staging ring (T4 counted vmcnt, DEPTH=3) kept from r10. NOTE: K-split changes
// per-element accumulation order -> absmax may leave exactly-0 (expected ~1e-5 rel).

#define BATCH 4
#define NPTS 8192
#define SETPTS (BATCH * NPTS)       // 32768
#define TOTPTS (2 * SETPTS)         // 65536
#define NSLOT 32                    // bf16 K-slots per point (30 used)
#define CHUNK_PTS 128               // col points staged per chunk = 4 tiles of 32
#define CSPLIT 8                    // col-splits per (dirb, rowblock)
#define COLS_PER (NPTS / CSPLIT)    // 1024 cols per block
#define CHUNKS_PER (COLS_PER / CHUNK_PTS)        // 8 chunks per block
#define CHUNK_BYTES (CHUNK_PTS * NSLOT * 2)      // 8192
#define DEPTH 3                     // ring-buffer depth
#define RT 2                        // 32-row tiles per wave (64 rows/wave)
#define ROWS_BLK (4 * RT * 32)      // 256 rows per block
#define RBLK (NPTS / ROWS_BLK)      // 32 row-blocks

typedef __attribute__((ext_vector_type(8))) short bf16x8;
typedef __attribute__((ext_vector_type(16))) float f32x16;

__device__ __forceinline__ float bf16rn(float v) {  // round-to-nearest-even to bf16 value
  unsigned u = __float_as_uint(v);
  u = (u + 0x7FFFu + ((u >> 16) & 1u)) & 0xFFFF0000u;
  return __uint_as_float(u);
}
__device__ __forceinline__ unsigned short b2u(float v) {  // bf16 bits of a bf16-valued f32
  return (unsigned short)(__float_as_uint(v) >> 16);
}

// Per point: s-vec (row role, carries the -2 factor) and t-vec (col role):
//   coord d: s[8d+]: [-2a,-2a,-2a,-2b,-2b,-2b,-2c,-2c]   t[8d+]: [d,e,f,d,e,f,d,e]
//     -> limb pairs ad,ae,af,bd,be,bf,cd,ce (drops only ~2^-36 c*f)
//   slots 24-26: s = split(|p|^2), t = 1 ; slots 27-29: s = 1, t = split(|q|^2); 30-31: 0.
__global__ __launch_bounds__(256) void chamfer_prep_kernel(
    const float* __restrict__ p1, const float* __restrict__ p2,
    unsigned short* __restrict__ sArr, unsigned short* __restrict__ tArr,
    unsigned int* __restrict__ wmin, float* __restrict__ out) {
  const int i = blockIdx.x * 256 + threadIdx.x;  // 0..65535
  const float* src = (i < SETPTS) ? (p1 + 3 * (size_t)i) : (p2 + 3 * (size_t)(i - SETPTS));
  const float co[3] = {src[0], src[1], src[2]};
  union { unsigned short u[32]; uint4 v[4]; } sv, tv;
#pragma unroll
  for (int d = 0; d < 3; ++d) {
    const float v = co[d];
    const float a = bf16rn(v), r1 = v - a;        // Sterbenz-exact residuals
    const float bb = bf16rn(r1), r2 = r1 - bb;
    const float cc = bf16rn(r2);
    const unsigned short as = b2u(-2.f * a), bs = b2u(-2.f * bb), cs2 = b2u(-2.f * cc);
    const unsigned short at = b2u(a), bt = b2u(bb), ct = b2u(cc);
    sv.u[8 * d + 0] = as; sv.u[8 * d + 1] = as; sv.u[8 * d + 2] = as;
    sv.u[8 * d + 3] = bs; sv.u[8 * d + 4] = bs; sv.u[8 * d + 5] = bs;
    sv.u[8 * d + 6] = cs2; sv.u[8 * d + 7] = cs2;
    tv.u[8 * d + 0] = at; tv.u[8 * d + 1] = bt; tv.u[8 * d + 2] = ct;
    tv.u[8 * d + 3] = at; tv.u[8 * d + 4] = bt; tv.u[8 * d + 5] = ct;
    tv.u[8 * d + 6] = at; tv.u[8 * d + 7] = bt;
  }
  const float sp = fmaf(co[0], co[0], fmaf(co[1], co[1], co[2] * co[2]));
  const float g = bf16rn(sp), q1 = sp - g;
  const float h = bf16rn(q1), q2 = q1 - h;
  const float ii = bf16rn(q2);
  sv.u[24] = b2u(g); sv.u[25] = b2u(h); sv.u[26] = b2u(ii);
  tv.u[24] = 0x3F80; tv.u[25] = 0x3F80; tv.u[26] = 0x3F80;  // bf16(1.0)
  sv.u[27] = 0x3F80; sv.u[28] = 0x3F80; sv.u[29] = 0x3F80;
  tv.u[27] = b2u(g); tv.u[28] = b2u(h); tv.u[29] = b2u(ii);
  sv.u[30] = 0; sv.u[31] = 0; tv.u[30] = 0; tv.u[31] = 0;
  uint4* sd = (uint4*)(sArr + (size_t)i * NSLOT);
  uint4* td = (uint4*)(tArr + (size_t)i * NSLOT);
#pragma unroll
  for (int k = 0; k < 4; ++k) { sd[k] = sv.v[k]; td[k] = tv.v[k]; }
  wmin[i] = 0x7F800000u;  // +inf bits: > any clamped finite float's bits
  if (i == 0) out[0] = 0.f;
}

// Block: 4 waves x 2 row-tiles(32) = 256 rows, 8 chunks (1024 cols) of its col-split.
// LDS chunk layout (pre-permuted global source, m173): slot s = jt*128 + q*32 + c,
// where jt = 32-col tile, q = 16B quarter of the point's 64B K-vector, c = col in tile.
// Reader: b0 = slot jt*128 + (l>>5)*32 + (l&31); b1 = +1024B (quarters 2,3). Linear,
// conflict-free ds_read_b128, and exactly the 32x32x16 B-fragment.
__global__ __launch_bounds__(256, 4) void chamfer_mfma_kernel(
    const unsigned short* __restrict__ sArr, const unsigned short* __restrict__ tArr,
    unsigned int* __restrict__ wmin) {
  const int bx = blockIdx.x;
  const int dirb = bx & 7;         // bx%8 -> XCD-aligned: per-XCD L2 sees one dirb's t-set
  const int rblk = (bx >> 3) & (RBLK - 1);  // 0..31 (256 rows each)
  const int csp = bx >> 8;         // 0..7 (1024 cols each)
  const int dir = dirb >> 2, b = dirb & 3;
  const unsigned short* sb = sArr + (size_t)((dir ? SETPTS : 0) + b * NPTS) * NSLOT;
  const unsigned short* tb = tArr + (size_t)((dir ? 0 : SETPTS) + b * NPTS) * NSLOT;
  unsigned int* wm = wmin + (size_t)dirb * NPTS;

  const int t = threadIdx.x;
  const int lane = t & 63, wid = t >> 6;
  const int l31 = lane & 31, kh = lane >> 5;  // col/row in tile, k-half

  __shared__ uint4 sbuf[DEPTH][CHUNK_BYTES / 16];  // 3 x 8 KB ring
  char* cs = (char*)sbuf;

  const int rowbase = rblk * ROWS_BLK + wid * (RT * 32);  // wave owns 64 rows = 2 tiles
  bf16x8 a0[RT], a1[RT];  // K-halves 0 (slots 0-15) and 1 (slots 16-31)
#pragma unroll
  for (int m = 0; m < RT; ++m) {
    const size_t rowoff = (size_t)(rowbase + m * 32 + l31) * NSLOT;
    a0[m] = *(const bf16x8*)(sb + rowoff + kh * 8);
    a1[m] = *(const bf16x8*)(sb + rowoff + 16 + kh * 8);
  }

  const char* gsrc[2];
#pragma unroll
  for (int k = 0; k < 2; ++k) {
    const int s = k * 256 + t;  // 0..511 slots: jt=s>>7, q=(s>>5)&3, c=s&31
    const int jt = s >> 7, q = (s >> 5) & 3, c = s & 31;
    gsrc[k] = (const char*)(tb + (size_t)(csp * COLS_PER + jt * 32 + c) * NSLOT + q * 8);
  }

  auto stage = [&](int chunk, int buf) {
#pragma unroll
    for (int k = 0; k < 2; ++k)
      __builtin_amdgcn_global_load_lds(
          (const __attribute__((address_space(1))) void*)(gsrc[k] + (size_t)chunk * CHUNK_BYTES),
          (__attribute__((address_space(3))) void*)(cs + buf * CHUNK_BYTES + (k * 256 + t) * 16),
          16, 0, 0);
  };

  f32x16 acc[RT];
#pragma unroll
  for (int m = 0; m < RT; ++m)
#pragma unroll
    for (int r = 0; r < 16; ++r) acc[m][r] = INFINITY;
  const f32x16 zero = {0.f, 0.f, 0.f, 0.f, 0.f, 0.f, 0.f, 0.f,
                       0.f, 0.f, 0.f, 0.f, 0.f, 0.f, 0.f, 0.f};

  stage(0, 0);  // prologue: chunks 0,1 in flight (4 loads/thread)
  stage(1, 1);

  const int bofs = ((kh * 32 + l31) * 16);  // per-lane B slot byte offset within a tile
  int cbuf = 0, ibuf = 2;
  for (int c = 0; c < CHUNKS_PER; ++c) {
    // T4: counted wait -- own chunk-c loads done, chunk c+1's 2 loads stay in flight.
    if (c + 1 < CHUNKS_PER) asm volatile("s_waitcnt vmcnt(2)" ::: "memory");
    else                    asm volatile("s_waitcnt vmcnt(0)" ::: "memory");
    __builtin_amdgcn_s_barrier();        // all waves' chunk-c loads landed; readers of
    __builtin_amdgcn_sched_barrier(0);   //  chunk c-1 all done
    if (c + 2 < CHUNKS_PER) {            // stage into the buffer chunk c-1 vacated
      stage(c + 2, ibuf);
      ibuf = (ibuf == DEPTH - 1) ? 0 : ibuf + 1;
    }
    const char* bbase = cs + cbuf * CHUNK_BYTES;
    __builtin_amdgcn_s_setprio(1);       // T5: favor the MFMA cluster
#pragma unroll
    for (int jt = 0; jt < 4; jt += 2) {  // 32-col tile PAIRS: min3 folds two results/op
      const char* tA = bbase + jt * 2048;
      const bf16x8 b0A = *(const bf16x8*)(tA + bofs);           // quarters 0,1 (K 0-15)
      const bf16x8 b1A = *(const bf16x8*)(tA + 1024 + bofs);    // quarters 2,3 (K 16-31)
      const bf16x8 b0B = *(const bf16x8*)(tA + 2048 + bofs);
      const bf16x8 b1B = *(const bf16x8*)(tA + 3072 + bofs);
#pragma unroll
      for (int m = 0; m < RT; ++m) {
        f32x16 dA = __builtin_amdgcn_mfma_f32_32x32x16_bf16(a0[m], b0A, zero, 0, 0, 0);
        dA = __builtin_amdgcn_mfma_f32_32x32x16_bf16(a1[m], b1A, dA, 0, 0, 0);
        f32x16 dB = __builtin_amdgcn_mfma_f32_32x32x16_bf16(a0[m], b0B, zero, 0, 0, 0);
        dB = __builtin_amdgcn_mfma_f32_32x32x16_bf16(a1[m], b1B, dB, 0, 0, 0);
#pragma unroll
        for (int r = 0; r < 16; ++r)
          acc[m][r] = fminf(fminf(acc[m][r], dA[r]), dB[r]);  // v_min3_f32
      }
    }
    __builtin_amdgcn_s_setprio(0);
    cbuf = (cbuf == DEPTH - 1) ? 0 : cbuf + 1;
  }

  // fold the 32 col-lanes (same kh half: xor masks 1..16 keep bit5) -> row-mins
#pragma unroll
  for (int mk = 1; mk <= 16; mk <<= 1) {
#pragma unroll
    for (int m = 0; m < RT; ++m)
#pragma unroll
      for (int r = 0; r < 16; ++r)
        acc[m][r] = fminf(acc[m][r], __shfl_xor(acc[m][r], mk, 64));
  }
  if (l31 == 0) {  // C/D: col=lane&31, row=(reg&3)+8*(reg>>2)+4*(lane>>5) [m74/m101]
#pragma unroll
    for (int m = 0; m < RT; ++m)
#pragma unroll
      for (int r = 0; r < 16; ++r) {
        const int row = rowbase + m * 32 + (r & 3) + 8 * (r >> 2) + 4 * kh;
        atomicMin(&wm[row], __float_as_uint(fmaxf(acc[m][r], 0.f)));
      }
  }
}

__global__ __launch_bounds__(256) void chamfer_reduce_kernel(const unsigned int* __restrict__ wmin,
                                                             float* __restrict__ out) {
  // 65536 elements; 64 blocks x 256 threads x 4 elems
  float s = 0.f;
  const int base = blockIdx.x * 1024 + threadIdx.x;
#pragma unroll
  for (int k = 0; k < 4; ++k) s += __uint_as_float(wmin[base + k * 256]);
#pragma unroll
  for (int off = 32; off > 0; off >>= 1) s += __shfl_down(s, off, 64);
  __shared__ float wsum[4];
  const int lane = threadIdx.x & 63, wid = threadIdx.x >> 6;
  if (lane == 0) wsum[wid] = s;
  __syncthreads();
  if (threadIdx.x == 0) atomicAdd(out, wsum[0] + wsum[1] + wsum[2] + wsum[3]);
}

extern "C" void kernel_launch(void* const* d_in, const int* in_sizes, int n_in,
                              void* d_out, int out_size, void* d_ws, size_t ws_size,
                              hipStream_t stream) {
  const float* p1 = (const float*)d_in[0];
  const float* p2 = (const float*)d_in[1];
  float* out = (float*)d_out;
  unsigned short* sArr = (unsigned short*)d_ws;                       // 4 MB
  unsigned short* tArr = (unsigned short*)((char*)d_ws + (4 << 20));  // 4 MB
  unsigned int* wmin = (unsigned int*)((char*)d_ws + (8 << 20));      // 256 KB

  chamfer_prep_kernel<<<dim3(TOTPTS / 256), dim3(256), 0, stream>>>(p1, p2, sArr, tArr, wmin, out);
  chamfer_mfma_kernel<<<dim3(8 * RBLK * CSPLIT), dim3(256), 0, stream>>>(sArr, tArr, wmin);
  chamfer_reduce_kernel<<<dim3(64), dim3(256), 0, stream>>>(wmin, out);
}